// Round 3
// baseline (120.194 us; speedup 1.0000x reference)
//
#include <hip/hip_runtime.h>
#include <hip/hip_fp16.h>

// CPDecoding: out[n] = sum_c prod_d lerp(coef[d][c], pos_d(n))
//
// R9 = DIAGNOSTIC round. R8's kernel exactly (dual-port gather: comps 0..15
// from LDS, comps 16..23 from a 6.3 KB L1-resident global mini-table), with
// the per-thread work repeated REPS=2 times (#pragma unroll 1 + asm keep-alive
// so rep 0 isn't DCE'd). Purpose: the decode kernel has sat at ~41.7 us for
// three structurally different variants, just BELOW the harness's ~44 us
// poison fills, so it never appeared in the rocprof top-5 and its counters
// (VGPR/spill traffic, SQ_LDS_BANK_CONFLICT, VALUBusy, Occupancy) have never
// been observed. Doubling the dispatch makes it top-1 without changing
// occupancy or per-point behavior. The rep loop is removed next round.

#define RES    256
#define NC     24
#define R0     124                 // first staged row
#define NR     132                 // staged rows
#define ROW_H  24                  // halves per LDS row (48 B stride): comps 0..15
#define STAGE_N (3 * 16 * NR)      // LDS staged elements (comps 0..15)
#define GTAB_N  (3 * 8 * NR)       // global mini-table elements (comps 16..23)
#define REPS   2                   // diagnostic work multiplier

struct PState {
    int ro[3];          // d*NR + i0  (shared row index for LDS and gtab)
    __half2 w[3];       // broadcast lerp weight per dim
};

__device__ __forceinline__ PState prep(float x, float y, float z) {
    // torch stacks coords (z, y, x) against dims 0, 1, 2
    const float coord[3] = {z, y, x};
    PState s;
    #pragma unroll
    for (int d = 0; d < 3; ++d) {
        float pos = (coord[d] + 1.0f) * 0.5f * 255.0f;   // match ref fp32 order
        float fl  = floorf(pos);
        float w   = pos - fl;
        int i0 = (int)fl - R0;
        i0 = max(0, min(i0, NR - 2));   // staged-range clamp (in-spec: no-op)
        s.ro[d] = d * NR + i0;
        s.w[d] = __float2half2_rn(w);
    }
    return s;
}

// lerp per dim, product across dims, reduce 8 comps -> f32
// (same pairing + f32 associativity as R6/R7/R8)
__device__ __forceinline__ float chunk_math(const uint4* v0, const uint4* v1,
                                            const PState& s) {
    __half2 p[4];
    #pragma unroll
    for (int d = 0; d < 3; ++d) {
        const __half2* h0 = (const __half2*)&v0[d];
        const __half2* h1 = (const __half2*)&v1[d];
        #pragma unroll
        for (int j = 0; j < 4; ++j) {
            __half2 l = __hfma2(s.w[d], __hsub2(h1[j], h0[j]), h0[j]);
            p[j] = (d == 0) ? l : __hmul2(p[j], l);
        }
    }
    float2 a = __half22float2(__hadd2(p[0], p[1]));
    float2 b = __half22float2(__hadd2(p[2], p[3]));
    return (a.x + a.y) + (b.x + b.y);
}

__device__ __forceinline__ float decode_point(const __half* __restrict__ lds,
                                              const __half* __restrict__ gtab,
                                              float x, float y, float z) {
    PState s = prep(x, y, z);

    // chunk 2 from the L1-resident mini-table: issue FIRST so the latency
    // hides under the two LDS chunks' reads + math
    uint4 g0[3], g1[3];
    #pragma unroll
    for (int d = 0; d < 3; ++d) {
        const __half* gr = gtab + s.ro[d] * 8;
        g0[d] = *(const uint4*)gr;          // row i0   (16 B)
        g1[d] = *(const uint4*)(gr + 8);    // row i0+1 (16 B)
    }

    // chunks 0..1 from LDS (6-batched ds_read_b128 per chunk: proven layout)
    float c0, c1;
    #pragma unroll
    for (int ch = 0; ch < 2; ++ch) {
        uint4 v0[3], v1[3];
        #pragma unroll
        for (int d = 0; d < 3; ++d) {
            const __half* r = lds + s.ro[d] * ROW_H + ch * 8;
            v0[d] = *(const uint4*)r;              // ds_read_b128 row i0
            v1[d] = *(const uint4*)(r + ROW_H);    // ds_read_b128 row i0+1
        }
        float c = chunk_math(v0, v1, s);
        if (ch == 0) c0 = c; else c1 = c;
    }

    float c2 = chunk_math(g0, g1, s);
    return (c0 + c1) + c2;
}

// pack coef[d][16+c][R0+i] -> gtab[(d*NR+i)*8 + c] as fp16 (6336 B total)
__global__ __launch_bounds__(512)
void cp_prep_kernel(const float* __restrict__ coef, __half* __restrict__ gtab) {
    int t = blockIdx.x * blockDim.x + threadIdx.x;
    if (t < GTAB_N) {
        int d = t / (NR * 8);
        int r = t - d * (NR * 8);
        int i = r >> 3;
        int c = r & 7;
        gtab[t] = __float2half(coef[(d * NC + 16 + c) * RES + R0 + i]);
    }
}

__global__ __launch_bounds__(512, 8)
void cp_decode_kernel(const float* __restrict__ pts,
                      const float* __restrict__ coef,
                      const __half* __restrict__ gtab,
                      float* __restrict__ out, int N) {
    __shared__ __align__(16) __half lds[3 * NR * ROW_H];   // 19008 B

    const int gtid = blockIdx.x * blockDim.x + threadIdx.x;
    const bool fast = (4 * gtid + 3 < N);

    // issue the coord loads first: their latency hides under LDS staging
    float4 q0, q1, q2;
    if (fast) {
        const float4* pv = (const float4*)(pts + 12 * (size_t)gtid);
        q0 = pv[0];   // x0 y0 z0 x1
        q1 = pv[1];   // y1 z1 x2 y2
        q2 = pv[2];   // z2 x3 y3 z3
    }

    // stage coef[d][c][R0+i] (comps 0..15) -> lds[(d*NR+i)*24 + c] as fp16
    for (int t = threadIdx.x; t < STAGE_N; t += blockDim.x) {
        int d = t / (16 * NR);
        int r = t - d * (16 * NR);
        int c = r / NR;            // 0..15
        int i = r - c * NR;
        lds[(d * NR + i) * ROW_H + c] = __float2half(coef[(d * NC + c) * RES + R0 + i]);
    }
    __syncthreads();

    if (fast) {
        #pragma unroll 1
        for (int rep = 0; rep < REPS; ++rep) {
            float4 res;
            res.x = decode_point(lds, gtab, q0.x, q0.y, q0.z);
            res.y = decode_point(lds, gtab, q0.w, q1.x, q1.y);
            res.z = decode_point(lds, gtab, q1.z, q1.w, q2.x);
            res.w = decode_point(lds, gtab, q2.y, q2.z, q2.w);
            // keep rep-0's computation live even though its store is dead
            asm volatile("" :: "v"(res.x), "v"(res.y), "v"(res.z), "v"(res.w));
            *(float4*)(out + 4 * (size_t)gtid) = res;
        }
    } else {
        // generic tail path (ragged N)
        #pragma unroll 1
        for (int rep = 0; rep < REPS; ++rep) {
            for (int n = 4 * gtid; n < N && n < 4 * gtid + 4; ++n) {
                float r = decode_point(lds, gtab,
                                       pts[3 * n], pts[3 * n + 1], pts[3 * n + 2]);
                asm volatile("" :: "v"(r));
                out[n] = r;
            }
        }
    }
}

extern "C" void kernel_launch(void* const* d_in, const int* in_sizes, int n_in,
                              void* d_out, int out_size, void* d_ws, size_t ws_size,
                              hipStream_t stream) {
    const float* pts  = (const float*)d_in[0];
    const float* coef = (const float*)d_in[1];
    float* out = (float*)d_out;
    __half* gtab = (__half*)d_ws;          // 6336 B mini-table in workspace
    const int N = in_sizes[0] / 3;

    cp_prep_kernel<<<dim3((GTAB_N + 511) / 512), dim3(512), 0, stream>>>(coef, gtab);

    // 4 consecutive points per thread: 1024 blocks x 512 thr at N = 2^21
    int blocks = (N + 4 * 512 - 1) / (4 * 512);
    if (blocks < 1) blocks = 1;
    cp_decode_kernel<<<dim3(blocks), dim3(512), 0, stream>>>(pts, coef, gtab, out, N);
}

// Round 4
// 87.451 us; speedup vs baseline: 1.3744x; 1.3744x over previous
//
#include <hip/hip_runtime.h>
#include <hip/hip_fp16.h>

// CPDecoding: out[n] = sum_c prod_d lerp(coef[d][c], pos_d(n))
//
// R10 = spill elimination. R9's counters finally exposed the real bottleneck:
// the fast path needs ~90 VGPRs (g-buf 24 + v-buf 24 + coords 12 + state/addr
// ~30) but the (512,8) launch bound squeezed allocation to 32 VGPRs + scratch
// -> ~110 MB of spill WRITE + ~60 MB spill FETCH per dispatch (measured
// WRITE_SIZE 125.6 MB vs 16 MB expected). Every structural optimization
// (R7 pipeline, R8 dual-port) was neutral because its extra live state went
// straight to HBM-backed scratch.
//
// Fix: phase-serialize decode_point so only ONE 6x-uint4 read buffer is ever
// live: gtab chunk (comps 16..23) is issued AND consumed first -> scalar c2,
// then LDS chunks 0..1 reuse the buffer. Peak pressure ~54 regs -> fits the
// 64-reg budget at (512,8), keeping 32 waves/CU. sched_barrier(0) fences pin
// the phase order (the scheduler would otherwise hoist LDS reads back across
// the gtab math and re-create the overlap/spill). gtab latency is now exposed
// per-point; 32 waves/CU of TLP hides it. Sum order (c0+c1)+c2 unchanged ->
// bitwise-same output. REPS diagnostic removed.
//
//  - comps 0..15 in LDS: rows 124..255, fp16, [d][i][c], 48 B row stride,
//    19 KB -> 4 blocks/CU at 512 thr.
//  - comps 16..23 in a 6.3 KB packed fp16 mini-table (d_ws), L1-resident,
//    read via global_load_dwordx4 on the VMEM path in parallel with LDS.

#define RES    256
#define NC     24
#define R0     124                 // first staged row
#define NR     132                 // staged rows
#define ROW_H  24                  // halves per LDS row (48 B stride): comps 0..15
#define STAGE_N (3 * 16 * NR)      // LDS staged elements (comps 0..15)
#define GTAB_N  (3 * 8 * NR)       // global mini-table elements (comps 16..23)

struct PState {
    int ro[3];          // d*NR + i0  (shared row index for LDS and gtab)
    __half2 w[3];       // broadcast lerp weight per dim
};

__device__ __forceinline__ PState prep(float x, float y, float z) {
    // torch stacks coords (z, y, x) against dims 0, 1, 2
    const float coord[3] = {z, y, x};
    PState s;
    #pragma unroll
    for (int d = 0; d < 3; ++d) {
        float pos = (coord[d] + 1.0f) * 0.5f * 255.0f;   // match ref fp32 order
        float fl  = floorf(pos);
        float w   = pos - fl;
        int i0 = (int)fl - R0;
        i0 = max(0, min(i0, NR - 2));   // staged-range clamp (in-spec: no-op)
        s.ro[d] = d * NR + i0;
        s.w[d] = __float2half2_rn(w);
    }
    return s;
}

// lerp per dim, product across dims, reduce 8 comps -> f32
// (same pairing + f32 associativity as R6..R9)
__device__ __forceinline__ float chunk_math(const uint4* v0, const uint4* v1,
                                            const PState& s) {
    __half2 p[4];
    #pragma unroll
    for (int d = 0; d < 3; ++d) {
        const __half2* h0 = (const __half2*)&v0[d];
        const __half2* h1 = (const __half2*)&v1[d];
        #pragma unroll
        for (int j = 0; j < 4; ++j) {
            __half2 l = __hfma2(s.w[d], __hsub2(h1[j], h0[j]), h0[j]);
            p[j] = (d == 0) ? l : __hmul2(p[j], l);
        }
    }
    float2 a = __half22float2(__hadd2(p[0], p[1]));
    float2 b = __half22float2(__hadd2(p[2], p[3]));
    return (a.x + a.y) + (b.x + b.y);
}

__device__ __forceinline__ float decode_point(const __half* __restrict__ lds,
                                              const __half* __restrict__ gtab,
                                              float x, float y, float z) {
    PState s = prep(x, y, z);

    uint4 b0[3], b1[3];   // the ONLY read buffer — reused by all 3 phases

    // phase 0: gtab chunk (comps 16..23) — issue, wait, consume immediately.
    #pragma unroll
    for (int d = 0; d < 3; ++d) {
        const __half* gr = gtab + s.ro[d] * 8;
        b0[d] = *(const uint4*)gr;          // row i0   (16 B)
        b1[d] = *(const uint4*)(gr + 8);    // row i0+1 (16 B)
    }
    float c2 = chunk_math(b0, b1, s);
    // reg-pressure fence: forbid hoisting the LDS-chunk reads above this point
    // (the overlap would push peak pressure back over the 64-reg budget)
    __builtin_amdgcn_sched_barrier(0);

    // phase 1: LDS chunk 0 (comps 0..7)
    #pragma unroll
    for (int d = 0; d < 3; ++d) {
        const __half* r = lds + s.ro[d] * ROW_H;
        b0[d] = *(const uint4*)r;              // ds_read_b128 row i0
        b1[d] = *(const uint4*)(r + ROW_H);    // ds_read_b128 row i0+1
    }
    float c0 = chunk_math(b0, b1, s);
    __builtin_amdgcn_sched_barrier(0);

    // phase 2: LDS chunk 1 (comps 8..15)
    #pragma unroll
    for (int d = 0; d < 3; ++d) {
        const __half* r = lds + s.ro[d] * ROW_H + 8;
        b0[d] = *(const uint4*)r;
        b1[d] = *(const uint4*)(r + ROW_H);
    }
    float c1 = chunk_math(b0, b1, s);
    __builtin_amdgcn_sched_barrier(0);

    return (c0 + c1) + c2;      // same order as R6..R9 -> bitwise-same
}

// pack coef[d][16+c][R0+i] -> gtab[(d*NR+i)*8 + c] as fp16 (6336 B total)
__global__ __launch_bounds__(512)
void cp_prep_kernel(const float* __restrict__ coef, __half* __restrict__ gtab) {
    int t = blockIdx.x * blockDim.x + threadIdx.x;
    if (t < GTAB_N) {
        int d = t / (NR * 8);
        int r = t - d * (NR * 8);
        int i = r >> 3;
        int c = r & 7;
        gtab[t] = __float2half(coef[(d * NC + 16 + c) * RES + R0 + i]);
    }
}

__global__ __launch_bounds__(512, 8)
void cp_decode_kernel(const float* __restrict__ pts,
                      const float* __restrict__ coef,
                      const __half* __restrict__ gtab,
                      float* __restrict__ out, int N) {
    __shared__ __align__(16) __half lds[3 * NR * ROW_H];   // 19008 B

    const int gtid = blockIdx.x * blockDim.x + threadIdx.x;
    const bool fast = (4 * gtid + 3 < N);

    // issue the coord loads first: their latency hides under LDS staging
    float4 q0, q1, q2;
    if (fast) {
        const float4* pv = (const float4*)(pts + 12 * (size_t)gtid);
        q0 = pv[0];   // x0 y0 z0 x1
        q1 = pv[1];   // y1 z1 x2 y2
        q2 = pv[2];   // z2 x3 y3 z3
    }

    // stage coef[d][c][R0+i] (comps 0..15) -> lds[(d*NR+i)*24 + c] as fp16
    for (int t = threadIdx.x; t < STAGE_N; t += blockDim.x) {
        int d = t / (16 * NR);
        int r = t - d * (16 * NR);
        int c = r / NR;            // 0..15
        int i = r - c * NR;
        lds[(d * NR + i) * ROW_H + c] = __float2half(coef[(d * NC + c) * RES + R0 + i]);
    }
    __syncthreads();

    if (fast) {
        float4 res;
        res.x = decode_point(lds, gtab, q0.x, q0.y, q0.z);
        res.y = decode_point(lds, gtab, q0.w, q1.x, q1.y);
        res.z = decode_point(lds, gtab, q1.z, q1.w, q2.x);
        res.w = decode_point(lds, gtab, q2.y, q2.z, q2.w);
        *(float4*)(out + 4 * (size_t)gtid) = res;
    } else {
        // generic tail path (ragged N)
        for (int n = 4 * gtid; n < N && n < 4 * gtid + 4; ++n) {
            out[n] = decode_point(lds, gtab,
                                  pts[3 * n], pts[3 * n + 1], pts[3 * n + 2]);
        }
    }
}

extern "C" void kernel_launch(void* const* d_in, const int* in_sizes, int n_in,
                              void* d_out, int out_size, void* d_ws, size_t ws_size,
                              hipStream_t stream) {
    const float* pts  = (const float*)d_in[0];
    const float* coef = (const float*)d_in[1];
    float* out = (float*)d_out;
    __half* gtab = (__half*)d_ws;          // 6336 B mini-table in workspace
    const int N = in_sizes[0] / 3;

    cp_prep_kernel<<<dim3((GTAB_N + 511) / 512), dim3(512), 0, stream>>>(coef, gtab);

    // 4 consecutive points per thread: 1024 blocks x 512 thr at N = 2^21
    int blocks = (N + 4 * 512 - 1) / (4 * 512);
    if (blocks < 1) blocks = 1;
    cp_decode_kernel<<<dim3(blocks), dim3(512), 0, stream>>>(pts, coef, gtab, out, N);
}